// Round 8
// baseline (83.798 us; speedup 1.0000x reference)
//
#include <hip/hip_runtime.h>
#include <hip/hip_bf16.h>

#define SEQL 4096
#define MROWS 32768
#define DMODEL 512
#define KFULL 1024

typedef __attribute__((ext_vector_type(8))) short bf16x8;
typedef __attribute__((ext_vector_type(4))) short s16x4;
typedef __attribute__((ext_vector_type(4))) float f32x4;

__device__ __forceinline__ short f2bf(float f) {
    union { float f; unsigned u; } v; v.f = f;
    unsigned r = v.u + 0x7FFFu + ((v.u >> 16) & 1u);
    return (short)(r >> 16);
}

// Newton for y^3/3 + y = x. |x| <= ~6 post-LN -> 5 iters, err well under bf16 floor.
__device__ __forceinline__ float nonsat(float x) {
    float y = x;
    #pragma unroll
    for (int i = 0; i < 5; ++i) {
        float y2  = y * y;
        float num = __builtin_fmaf(y2 * y, 0.66666667f, x);
        y = num * __builtin_amdgcn_rcpf(y2 + 1.0f);
    }
    return y;
}

// Barrier that waits only on LDS ops (cross-wave dependency), NOT on this
// wave's private global->register loads. __syncthreads() would emit
// s_waitcnt vmcnt(0) and kill all prefetch once per k-step.
__device__ __forceinline__ void lgkm_barrier() {
    asm volatile("s_waitcnt lgkmcnt(0)" ::: "memory");
    __builtin_amdgcn_sched_barrier(0);
    __builtin_amdgcn_s_barrier();
}

// W (512x1024 f32 [n][k]) -> fragment-tiled bf16:
// frag f = (k/32)*32 + (n/16); lane = ((k/8)&3)*16 + (n&15); elems k..k+7.
__global__ __launch_bounds__(256) void cvt_w(const float* __restrict__ W,
                                             short* __restrict__ Wbf) {
    int t8 = blockIdx.x * 256 + threadIdx.x;
    int n = t8 >> 7;
    int k = (t8 & 127) << 3;
    f32x4 lo = *(const f32x4*)(W + (size_t)n * KFULL + k);
    f32x4 hi = *(const f32x4*)(W + (size_t)n * KFULL + k + 4);
    bf16x8 v;
    v[0]=f2bf(lo[0]); v[1]=f2bf(lo[1]); v[2]=f2bf(lo[2]); v[3]=f2bf(lo[3]);
    v[4]=f2bf(hi[0]); v[5]=f2bf(hi[1]); v[6]=f2bf(hi[2]); v[7]=f2bf(hi[3]);
    int f    = (k >> 5) * 32 + (n >> 4);
    int lane = ((k >> 3) & 3) * 16 + (n & 15);
    *(bf16x8*)(Wbf + (size_t)f * 512 + lane * 8) = v;
}

// pe_gemm (swapped operands): P[l][n] = (pe @ W2^T)[l][n] + bias[n]
// 16 l-rows x 512 cols per block, 4 waves, BK=64, K=512, grid 256.
__global__ __launch_bounds__(256, 2) void pe_gemm(const float* __restrict__ pe,
                                                  const short* __restrict__ Wbf,
                                                  const float* __restrict__ bias,
                                                  float* __restrict__ P) {
    __shared__ short As[2][16 * 64];
    const int tid  = threadIdx.x;
    const int wn   = tid >> 6;
    const int lane = tid & 63;
    const int l4   = lane & 15;
    const int kg   = lane >> 4;
    const int l0   = blockIdx.x * 16;

    f32x4 acc[8];
    #pragma unroll
    for (int t = 0; t < 8; ++t) acc[t] = (f32x4){0.f,0.f,0.f,0.f};

    const int ar = tid >> 4;
    const int kc = (tid & 15) << 2;
    const int sidx = (ar * 64 + kc) ^ ((ar & 7) << 3);
    const float* xp = pe + (size_t)(l0 + ar) * DMODEL + kc;

    {
        f32x4 x0 = *(const f32x4*)xp;
        s16x4 w;
        w[0]=f2bf(x0[0]); w[1]=f2bf(x0[1]); w[2]=f2bf(x0[2]); w[3]=f2bf(x0[3]);
        *(s16x4*)&As[0][sidx] = w;
    }
    f32x4 xv = *(const f32x4*)(xp + 64);

    #pragma unroll
    for (int ks = 0; ks < 8; ++ks) {
        const int cur = ks & 1;
        lgkm_barrier();
        if (ks < 7) {
            s16x4 w;
            w[0]=f2bf(xv[0]); w[1]=f2bf(xv[1]); w[2]=f2bf(xv[2]); w[3]=f2bf(xv[3]);
            *(s16x4*)&As[cur ^ 1][sidx] = w;
        }
        if (ks < 6) xv = *(const f32x4*)(xp + (ks + 2) * 64);
        #pragma unroll
        for (int ksub = 0; ksub < 2; ++ksub) {
            int bidx = (l4 * 64 + ksub * 32 + kg * 8) ^ ((l4 & 7) << 3);
            bf16x8 bx = *(const bf16x8*)&As[cur][bidx];
            const short* ap = Wbf + (size_t)((16 + ks * 2 + ksub) * 32 + wn * 8) * 512 + lane * 8;
            __builtin_amdgcn_s_setprio(1);
            #pragma unroll
            for (int t = 0; t < 8; ++t) {
                bf16x8 aw = *(const bf16x8*)(ap + (size_t)t * 512);
                acc[t] = __builtin_amdgcn_mfma_f32_16x16x32_bf16(aw, bx, acc[t], 0, 0, 0);
            }
            __builtin_amdgcn_s_setprio(0);
        }
    }

    #pragma unroll
    for (int t = 0; t < 8; ++t) {
        int n = wn * 128 + t * 16 + kg * 4;
        f32x4 b4 = *(const f32x4*)(bias + n);
        f32x4 v = acc[t] + b4;
        *(f32x4*)(P + (size_t)(l0 + l4) * DMODEL + n) = v;
    }
}

// main (swapped operands): out = nonsat(LN(x @ W1^T + P[m>>3]))
// 64 m-rows x 512 cols per block, 4 waves, BK=64, K=512, 4 m-frags/wave.
// C layout: lane holds row m = mi*16 + (lane&15), cols n = wn*128 + t*16 + kg*4 + j.
__global__ __launch_bounds__(256, 2) void main_fused(
    const float* __restrict__ x, const short* __restrict__ Wbf,
    const float* __restrict__ P, const float* __restrict__ gamma,
    const float* __restrict__ beta, float* __restrict__ out)
{
    __shared__ short As[2][64 * 64];     // 16 KB
    __shared__ float P_lds[8 * 512];     // 16 KB
    __shared__ float GB[2][512];         // 4 KB
    __shared__ float red[4][64][2];      // 2 KB

    const int tid  = threadIdx.x;
    const int wn   = tid >> 6;
    const int lane = tid & 63;
    const int l4   = lane & 15;
    const int kg   = lane >> 4;
    const int m0   = blockIdx.x * 64;
    const int l0   = m0 >> 3;

    f32x4 acc[4][8];
    #pragma unroll
    for (int mi = 0; mi < 4; ++mi)
        #pragma unroll
        for (int t = 0; t < 8; ++t) acc[mi][t] = (f32x4){0.f,0.f,0.f,0.f};

    // x staging: thread -> row ar = tid/4, 16 k-elems at (tid&3)*16
    const int ar = tid >> 2;
    const int kc = (tid & 3) << 4;
    const int sw = (ar & 7) << 3;
    const int sb = ar * 64 + kc;
    const float* xp = x + (size_t)(m0 + ar) * DMODEL + kc;

    {   // step-0 stage
        f32x4 x0[4];
        #pragma unroll
        for (int i = 0; i < 4; ++i) x0[i] = *(const f32x4*)(xp + i * 4);
        bf16x8 v0, v1;
        v0[0]=f2bf(x0[0][0]); v0[1]=f2bf(x0[0][1]); v0[2]=f2bf(x0[0][2]); v0[3]=f2bf(x0[0][3]);
        v0[4]=f2bf(x0[1][0]); v0[5]=f2bf(x0[1][1]); v0[6]=f2bf(x0[1][2]); v0[7]=f2bf(x0[1][3]);
        v1[0]=f2bf(x0[2][0]); v1[1]=f2bf(x0[2][1]); v1[2]=f2bf(x0[2][2]); v1[3]=f2bf(x0[2][3]);
        v1[4]=f2bf(x0[3][0]); v1[5]=f2bf(x0[3][1]); v1[6]=f2bf(x0[3][2]); v1[7]=f2bf(x0[3][3]);
        *(bf16x8*)&As[0][sb ^ sw]       = v0;
        *(bf16x8*)&As[0][(sb + 8) ^ sw] = v1;
    }
    f32x4 xin[4];
    #pragma unroll
    for (int i = 0; i < 4; ++i) xin[i] = *(const f32x4*)(xp + 64 + i * 4);

    f32x4 pv[4], gb;

    #pragma unroll
    for (int ks = 0; ks < 8; ++ks) {
        const int cur = ks & 1;
        lgkm_barrier();   // waits LDS only; x/B/P prefetches stay in flight
        if (ks < 7) {
            bf16x8 v0, v1;
            v0[0]=f2bf(xin[0][0]); v0[1]=f2bf(xin[0][1]); v0[2]=f2bf(xin[0][2]); v0[3]=f2bf(xin[0][3]);
            v0[4]=f2bf(xin[1][0]); v0[5]=f2bf(xin[1][1]); v0[6]=f2bf(xin[1][2]); v0[7]=f2bf(xin[1][3]);
            v1[0]=f2bf(xin[2][0]); v1[1]=f2bf(xin[2][1]); v1[2]=f2bf(xin[2][2]); v1[3]=f2bf(xin[2][3]);
            v1[4]=f2bf(xin[3][0]); v1[5]=f2bf(xin[3][1]); v1[6]=f2bf(xin[3][2]); v1[7]=f2bf(xin[3][3]);
            *(bf16x8*)&As[cur ^ 1][sb ^ sw]       = v0;
            *(bf16x8*)&As[cur ^ 1][(sb + 8) ^ sw] = v1;
        }
        if (ks < 6) {
            #pragma unroll
            for (int i = 0; i < 4; ++i) xin[i] = *(const f32x4*)(xp + (ks + 2) * 64 + i * 4);
        }
        if (ks == 6) {
            // epilogue operands; ~2 k-steps of MFMA cover the latency
            const float* Pg = P + (size_t)l0 * DMODEL;
            #pragma unroll
            for (int i = 0; i < 4; ++i) pv[i] = *(const f32x4*)(Pg + i * 1024 + tid * 4);
            int c = tid * 4;
            const float* gsrc = (tid < 128) ? (gamma + c) : (beta + c - 512);
            gb = *(const f32x4*)gsrc;
        }
        #pragma unroll
        for (int ksub = 0; ksub < 2; ++ksub) {
            const short* bp = Wbf + (size_t)((ks * 2 + ksub) * 32 + wn * 8) * 512 + lane * 8;
            bf16x8 aw[8];
            #pragma unroll
            for (int t = 0; t < 8; ++t) aw[t] = *(const bf16x8*)(bp + (size_t)t * 512);
            bf16x8 bx[4];
            #pragma unroll
            for (int mi = 0; mi < 4; ++mi) {
                int idx = ((mi * 16 + l4) * 64 + ksub * 32 + kg * 8) ^ ((l4 & 7) << 3);
                bx[mi] = *(const bf16x8*)&As[cur][idx];
            }
            __builtin_amdgcn_s_setprio(1);
            #pragma unroll
            for (int t = 0; t < 8; ++t)
                #pragma unroll
                for (int mi = 0; mi < 4; ++mi)
                    acc[mi][t] = __builtin_amdgcn_mfma_f32_16x16x32_bf16(aw[t], bx[mi], acc[mi][t], 0, 0, 0);
            __builtin_amdgcn_s_setprio(0);
        }
    }

    // ---- stage P (flat, conflict-free) + gamma/beta to LDS ----
    #pragma unroll
    for (int i = 0; i < 4; ++i) *(f32x4*)&P_lds[i * 1024 + tid * 4] = pv[i];
    {
        int c = tid * 4;
        if (tid < 128) *(f32x4*)&GB[0][c]       = gb;
        else           *(f32x4*)&GB[1][c - 512] = gb;
    }
    __syncthreads();

    // ---- add P (broadcast LDS reads) ----
    #pragma unroll
    for (int mi = 0; mi < 4; ++mi) {
        int lp = mi * 2 + (l4 >> 3);
        #pragma unroll
        for (int t = 0; t < 8; ++t) {
            f32x4 p4 = *(const f32x4*)&P_lds[lp * 512 + wn * 128 + t * 16 + kg * 4];
            acc[mi][t] += p4;
        }
    }

    // ---- LN stats: in-register row sums + 2-step kg reduction ----
    float S[4], Q[4];
    #pragma unroll
    for (int mi = 0; mi < 4; ++mi) {
        float s = 0.f, q = 0.f;
        #pragma unroll
        for (int t = 0; t < 8; ++t)
            #pragma unroll
            for (int j = 0; j < 4; ++j) {
                float v = acc[mi][t][j];
                s += v; q = __builtin_fmaf(v, v, q);
            }
        s += __shfl_xor(s, 16); q += __shfl_xor(q, 16);
        s += __shfl_xor(s, 32); q += __shfl_xor(q, 32);
        S[mi] = s; Q[mi] = q;
    }
    if (lane < 16) {
        #pragma unroll
        for (int mi = 0; mi < 4; ++mi) {
            red[wn][mi * 16 + l4][0] = S[mi];
            red[wn][mi * 16 + l4][1] = Q[mi];
        }
    }
    __syncthreads();

    // ---- normalize (2 fma/elem) + nonsat + vector stores ----
    #pragma unroll
    for (int mi = 0; mi < 4; ++mi) {
        int r = mi * 16 + l4;
        float Ss = red[0][r][0] + red[1][r][0] + red[2][r][0] + red[3][r][0];
        float Qs = red[0][r][1] + red[1][r][1] + red[2][r][1] + red[3][r][1];
        float mean = Ss * (1.0f / 512.0f);
        float var  = Qs * (1.0f / 512.0f) - mean * mean;
        float rstd = rsqrtf(var + 1e-5f);
        float nmrs = -mean * rstd;
        float* orow = out + (size_t)(m0 + r) * DMODEL;
        #pragma unroll
        for (int t = 0; t < 8; ++t) {
            int n = wn * 128 + t * 16 + kg * 4;
            f32x4 g4 = *(const f32x4*)&GB[0][n];
            f32x4 b4 = *(const f32x4*)&GB[1][n];
            f32x4 o;
            #pragma unroll
            for (int j = 0; j < 4; ++j) {
                float z = __builtin_fmaf(acc[mi][t][j], rstd, nmrs);
                float v = __builtin_fmaf(z, g4[j], b4[j]);
                o[j] = nonsat(v);
            }
            *(f32x4*)(orow + n) = o;
        }
    }
}

// ---------- fallback (no workspace) ----------
__global__ __launch_bounds__(256) void fallback_fwd(
    const float* __restrict__ x, const float* __restrict__ Wf,
    const float* __restrict__ bias, const float* __restrict__ gamma,
    const float* __restrict__ beta, const float* __restrict__ pe,
    float* __restrict__ out)
{
    const int tid  = threadIdx.x;
    const int wave = tid >> 6;
    const int lane = tid & 63;
    const int lrow = lane & 15;
    const int kgrp = lane >> 4;
    const int n0   = wave * 128;
    const int m0   = blockIdx.x * 32;

    f32x4 acc[2][8];
    #pragma unroll
    for (int a = 0; a < 2; ++a)
        #pragma unroll
        for (int t = 0; t < 8; ++t) acc[a][t] = (f32x4){0.f,0.f,0.f,0.f};

    const int mA[2] = { m0 + lrow, m0 + 16 + lrow };
    for (int ks = 0; ks < 32; ++ks) {
        const int kb = ks * 32 + kgrp * 8;
        bf16x8 afrag[2];
        #pragma unroll
        for (int a = 0; a < 2; ++a) {
            const float* src = (kb < 512)
                ? (x  + (size_t)mA[a] * 512 + kb)
                : (pe + (size_t)(mA[a] >> 3) * 512 + (kb - 512));
            f32x4 lo = *(const f32x4*)src;
            f32x4 hi = *(const f32x4*)(src + 4);
            bf16x8 v;
            v[0]=f2bf(lo[0]); v[1]=f2bf(lo[1]); v[2]=f2bf(lo[2]); v[3]=f2bf(lo[3]);
            v[4]=f2bf(hi[0]); v[5]=f2bf(hi[1]); v[6]=f2bf(hi[2]); v[7]=f2bf(hi[3]);
            afrag[a] = v;
        }
        #pragma unroll
        for (int t = 0; t < 8; ++t) {
            const int n = n0 + t * 16 + lrow;
            const float* wsrc = Wf + (size_t)n * KFULL + kb;
            f32x4 lo = *(const f32x4*)wsrc;
            f32x4 hi = *(const f32x4*)(wsrc + 4);
            bf16x8 bfr;
            bfr[0]=f2bf(lo[0]); bfr[1]=f2bf(lo[1]); bfr[2]=f2bf(lo[2]); bfr[3]=f2bf(lo[3]);
            bfr[4]=f2bf(hi[0]); bfr[5]=f2bf(hi[1]); bfr[6]=f2bf(hi[2]); bfr[7]=f2bf(hi[3]);
            acc[0][t] = __builtin_amdgcn_mfma_f32_16x16x32_bf16(afrag[0], bfr, acc[0][t], 0, 0, 0);
            acc[1][t] = __builtin_amdgcn_mfma_f32_16x16x32_bf16(afrag[1], bfr, acc[1][t], 0, 0, 0);
        }
    }
    __shared__ float red[4][32][2];
    float bcol[8], gcol[8], ecol[8];
    #pragma unroll
    for (int t = 0; t < 8; ++t) {
        const int n = n0 + t * 16 + lrow;
        bcol[t] = bias[n]; gcol[t] = gamma[n]; ecol[t] = beta[n];
    }
    #pragma unroll
    for (int a = 0; a < 2; ++a)
        #pragma unroll
        for (int t = 0; t < 8; ++t)
            #pragma unroll
            for (int j = 0; j < 4; ++j) acc[a][t][j] += bcol[t];
    float sm[2][4], sq[2][4];
    #pragma unroll
    for (int a = 0; a < 2; ++a)
        #pragma unroll
        for (int j = 0; j < 4; ++j) {
            float s = 0.f, q = 0.f;
            #pragma unroll
            for (int t = 0; t < 8; ++t) { float v = acc[a][t][j]; s += v; q += v * v; }
            #pragma unroll
            for (int msk = 1; msk <= 8; msk <<= 1) {
                s += __shfl_xor(s, msk, 64);
                q += __shfl_xor(q, msk, 64);
            }
            sm[a][j] = s; sq[a][j] = q;
        }
    if (lrow == 0) {
        #pragma unroll
        for (int a = 0; a < 2; ++a)
            #pragma unroll
            for (int j = 0; j < 4; ++j) {
                int r = a * 16 + kgrp * 4 + j;
                red[wave][r][0] = sm[a][j];
                red[wave][r][1] = sq[a][j];
            }
    }
    __syncthreads();
    #pragma unroll
    for (int a = 0; a < 2; ++a)
        #pragma unroll
        for (int j = 0; j < 4; ++j) {
            const int r = a * 16 + kgrp * 4 + j;
            float Ss = red[0][r][0] + red[1][r][0] + red[2][r][0] + red[3][r][0];
            float Qs = red[0][r][1] + red[1][r][1] + red[2][r][1] + red[3][r][1];
            float mean = Ss * (1.0f / 512.0f);
            float var  = Qs * (1.0f / 512.0f) - mean * mean;
            float rstd = rsqrtf(var + 1e-5f);
            const int m = m0 + a * 16 + kgrp * 4 + j;
            float* orow = out + (size_t)m * 512;
            #pragma unroll
            for (int t = 0; t < 8; ++t) {
                const int n = n0 + t * 16 + lrow;
                float v = (acc[a][t][j] - mean) * rstd * gcol[t] + ecol[t];
                orow[n] = nonsat(v);
            }
        }
}

extern "C" void kernel_launch(void* const* d_in, const int* in_sizes, int n_in,
                              void* d_out, int out_size, void* d_ws, size_t ws_size,
                              hipStream_t stream) {
    const float* x     = (const float*)d_in[0];
    const float* W     = (const float*)d_in[1];
    const float* bias  = (const float*)d_in[2];
    const float* gamma = (const float*)d_in[3];
    const float* beta  = (const float*)d_in[4];
    const float* pe    = (const float*)d_in[5];
    float* out = (float*)d_out;

    const size_t WBF_BYTES = (size_t)KFULL * DMODEL * sizeof(short);   // 1 MB
    const size_t P_BYTES   = (size_t)SEQL * DMODEL * sizeof(float);    // 8 MB

    if (ws_size >= WBF_BYTES + P_BYTES) {
        short* Wbf = (short*)d_ws;
        float* P   = (float*)((char*)d_ws + WBF_BYTES);
        cvt_w<<<dim3((DMODEL * KFULL) / (256 * 8)), dim3(256), 0, stream>>>(W, Wbf);
        pe_gemm<<<dim3(SEQL / 16), dim3(256), 0, stream>>>(pe, Wbf, bias, P);
        main_fused<<<dim3(MROWS / 64), dim3(256), 0, stream>>>(x, Wbf, P, gamma, beta, out);
    } else {
        fallback_fwd<<<dim3(MROWS / 32), dim3(256), 0, stream>>>(x, W, bias, gamma, beta, pe, out);
    }
}

// Round 9
// 61.430 us; speedup vs baseline: 1.3641x; 1.3641x over previous
//
#include <hip/hip_runtime.h>
#include <hip/hip_bf16.h>

#define SEQL 4096
#define MROWS 32768
#define DMODEL 512
#define KFULL 1024

typedef __attribute__((ext_vector_type(8))) short bf16x8;
typedef __attribute__((ext_vector_type(4))) short s16x4;
typedef __attribute__((ext_vector_type(4))) float f32x4;

__device__ __forceinline__ short f2bf(float f) {
    union { float f; unsigned u; } v; v.f = f;
    unsigned r = v.u + 0x7FFFu + ((v.u >> 16) & 1u);
    return (short)(r >> 16);
}

// Newton for y^3/3 + y = x. |x| <= ~6 post-LN -> 5 iters, err well under bf16 floor.
__device__ __forceinline__ float nonsat(float x) {
    float y = x;
    #pragma unroll
    for (int i = 0; i < 5; ++i) {
        float y2  = y * y;
        float num = __builtin_fmaf(y2 * y, 0.66666667f, x);
        y = num * __builtin_amdgcn_rcpf(y2 + 1.0f);
    }
    return y;
}

// W (512x1024 f32 [n][k]) -> fragment-tiled bf16:
// frag f = (k/32)*32 + (n/16); lane = ((k/8)&3)*16 + (n&15); elems k..k+7.
__global__ __launch_bounds__(256) void cvt_w(const float* __restrict__ W,
                                             short* __restrict__ Wbf) {
    int t8 = blockIdx.x * 256 + threadIdx.x;
    int n = t8 >> 7;
    int k = (t8 & 127) << 3;
    f32x4 lo = *(const f32x4*)(W + (size_t)n * KFULL + k);
    f32x4 hi = *(const f32x4*)(W + (size_t)n * KFULL + k + 4);
    bf16x8 v;
    v[0]=f2bf(lo[0]); v[1]=f2bf(lo[1]); v[2]=f2bf(lo[2]); v[3]=f2bf(lo[3]);
    v[4]=f2bf(hi[0]); v[5]=f2bf(hi[1]); v[6]=f2bf(hi[2]); v[7]=f2bf(hi[3]);
    int f    = (k >> 5) * 32 + (n >> 4);
    int lane = ((k >> 3) & 3) * 16 + (n & 15);
    *(bf16x8*)(Wbf + (size_t)f * 512 + lane * 8) = v;
}

// pe_gemm (swapped operands): P[l][n] = (pe @ W2^T)[l][n] + bias[n]
// 32 l-rows x 512 cols per block, 4 waves, BK=64, K=512, 2 m-frags/wave (r6 config).
__global__ __launch_bounds__(256, 2) void pe_gemm(const float* __restrict__ pe,
                                                  const short* __restrict__ Wbf,
                                                  const float* __restrict__ bias,
                                                  float* __restrict__ P) {
    __shared__ short As[2][32 * 64];
    const int tid  = threadIdx.x;
    const int wn   = tid >> 6;
    const int lane = tid & 63;
    const int l4   = lane & 15;
    const int kg   = lane >> 4;
    const int l0   = blockIdx.x * 32;

    f32x4 acc[2][8];
    #pragma unroll
    for (int mi = 0; mi < 2; ++mi)
        #pragma unroll
        for (int t = 0; t < 8; ++t) acc[mi][t] = (f32x4){0.f,0.f,0.f,0.f};

    const int ar = tid >> 3;
    const int kc = (tid & 7) << 3;
    const int sw = (ar & 7) << 3;
    const int sb = ar * 64 + kc;
    const float* xp = pe + (size_t)(l0 + ar) * DMODEL + kc;

    {   // step-0 stage
        f32x4 a = *(const f32x4*)xp, b = *(const f32x4*)(xp + 4);
        bf16x8 v;
        v[0]=f2bf(a[0]); v[1]=f2bf(a[1]); v[2]=f2bf(a[2]); v[3]=f2bf(a[3]);
        v[4]=f2bf(b[0]); v[5]=f2bf(b[1]); v[6]=f2bf(b[2]); v[7]=f2bf(b[3]);
        *(bf16x8*)&As[0][sb ^ sw] = v;
    }
    f32x4 xa = *(const f32x4*)(xp + 64), xb = *(const f32x4*)(xp + 68);

    #pragma unroll
    for (int ks = 0; ks < 8; ++ks) {
        const int cur = ks & 1;
        __syncthreads();
        if (ks < 7) {
            bf16x8 v;
            v[0]=f2bf(xa[0]); v[1]=f2bf(xa[1]); v[2]=f2bf(xa[2]); v[3]=f2bf(xa[3]);
            v[4]=f2bf(xb[0]); v[5]=f2bf(xb[1]); v[6]=f2bf(xb[2]); v[7]=f2bf(xb[3]);
            *(bf16x8*)&As[cur ^ 1][sb ^ sw] = v;
        }
        if (ks < 6) {
            xa = *(const f32x4*)(xp + (ks + 2) * 64);
            xb = *(const f32x4*)(xp + (ks + 2) * 64 + 4);
        }
        #pragma unroll
        for (int ksub = 0; ksub < 2; ++ksub) {
            const short* bp = Wbf + (size_t)((16 + ks * 2 + ksub) * 32 + wn * 8) * 512 + lane * 8;
            bf16x8 aw[8];
            #pragma unroll
            for (int t = 0; t < 8; ++t) aw[t] = *(const bf16x8*)(bp + (size_t)t * 512);
            bf16x8 bx[2];
            #pragma unroll
            for (int mi = 0; mi < 2; ++mi) {
                int idx = ((mi * 16 + l4) * 64 + ksub * 32 + kg * 8) ^ ((l4 & 7) << 3);
                bx[mi] = *(const bf16x8*)&As[cur][idx];
            }
            __builtin_amdgcn_s_setprio(1);
            #pragma unroll
            for (int t = 0; t < 8; ++t)
                #pragma unroll
                for (int mi = 0; mi < 2; ++mi)
                    acc[mi][t] = __builtin_amdgcn_mfma_f32_16x16x32_bf16(aw[t], bx[mi], acc[mi][t], 0, 0, 0);
            __builtin_amdgcn_s_setprio(0);
        }
    }

    #pragma unroll
    for (int mi = 0; mi < 2; ++mi)
        #pragma unroll
        for (int t = 0; t < 8; ++t) {
            int n = wn * 128 + t * 16 + kg * 4;
            f32x4 b4 = *(const f32x4*)(bias + n);
            f32x4 v = acc[mi][t] + b4;
            *(f32x4*)(P + (size_t)(l0 + mi * 16 + l4) * DMODEL + n) = v;
        }
}

// main (swapped operands): out = nonsat(LN(x @ W1^T + P[m>>3]))
// 32 m-rows x 512 cols per block, 4 waves, BK=64, K=512, 2 m-frags/wave.
// acc = 64 AGPR -> __launch_bounds__(256,3) targets 3 blocks/CU (12 waves/CU)
// so co-resident blocks at different phases overlap MFMA/VALU/memory.
__global__ __launch_bounds__(256, 3) void main_fused(
    const float* __restrict__ x, const short* __restrict__ Wbf,
    const float* __restrict__ P, const float* __restrict__ gamma,
    const float* __restrict__ beta, float* __restrict__ out)
{
    __shared__ short As[2][32 * 64];     // 8 KB
    __shared__ float P_lds[4 * 512];     // 8 KB
    __shared__ float GB[2][512];         // 4 KB
    __shared__ float red[4][32][2];      // 1 KB

    const int tid  = threadIdx.x;
    const int wn   = tid >> 6;
    const int lane = tid & 63;
    const int l4   = lane & 15;
    const int kg   = lane >> 4;
    const int m0   = blockIdx.x * 32;
    const int l0   = m0 >> 3;

    f32x4 acc[2][8];
    #pragma unroll
    for (int mi = 0; mi < 2; ++mi)
        #pragma unroll
        for (int t = 0; t < 8; ++t) acc[mi][t] = (f32x4){0.f,0.f,0.f,0.f};

    // x staging: thread -> row ar = tid/8, 8 k-elems at (tid&7)*8
    const int ar = tid >> 3;
    const int kc = (tid & 7) << 3;
    const int sw = (ar & 7) << 3;
    const int sb = ar * 64 + kc;
    const float* xp = x + (size_t)(m0 + ar) * DMODEL + kc;

    {   // step-0 stage
        f32x4 a = *(const f32x4*)xp, b = *(const f32x4*)(xp + 4);
        bf16x8 v;
        v[0]=f2bf(a[0]); v[1]=f2bf(a[1]); v[2]=f2bf(a[2]); v[3]=f2bf(a[3]);
        v[4]=f2bf(b[0]); v[5]=f2bf(b[1]); v[6]=f2bf(b[2]); v[7]=f2bf(b[3]);
        *(bf16x8*)&As[0][sb ^ sw] = v;
    }
    f32x4 xa = *(const f32x4*)(xp + 64), xb = *(const f32x4*)(xp + 68);

    f32x4 pv[2], gb;

    #pragma unroll
    for (int ks = 0; ks < 8; ++ks) {
        const int cur = ks & 1;
        __syncthreads();
        if (ks < 7) {
            bf16x8 v;
            v[0]=f2bf(xa[0]); v[1]=f2bf(xa[1]); v[2]=f2bf(xa[2]); v[3]=f2bf(xa[3]);
            v[4]=f2bf(xb[0]); v[5]=f2bf(xb[1]); v[6]=f2bf(xb[2]); v[7]=f2bf(xb[3]);
            *(bf16x8*)&As[cur ^ 1][sb ^ sw] = v;
        }
        if (ks < 6) {
            xa = *(const f32x4*)(xp + (ks + 2) * 64);
            xb = *(const f32x4*)(xp + (ks + 2) * 64 + 4);
        }
        if (ks == 6) {
            // epilogue operands; ~2 k-steps of MFMA cover the latency
            const float* Pg = P + (size_t)l0 * DMODEL;
            #pragma unroll
            for (int i = 0; i < 2; ++i) pv[i] = *(const f32x4*)(Pg + i * 1024 + tid * 4);
            int c = tid * 4;
            const float* gsrc = (tid < 128) ? (gamma + c) : (beta + c - 512);
            gb = *(const f32x4*)gsrc;
        }
        #pragma unroll
        for (int ksub = 0; ksub < 2; ++ksub) {
            const short* bp = Wbf + (size_t)((ks * 2 + ksub) * 32 + wn * 8) * 512 + lane * 8;
            bf16x8 aw[8];
            #pragma unroll
            for (int t = 0; t < 8; ++t) aw[t] = *(const bf16x8*)(bp + (size_t)t * 512);
            bf16x8 bx[2];
            #pragma unroll
            for (int mi = 0; mi < 2; ++mi) {
                int idx = ((mi * 16 + l4) * 64 + ksub * 32 + kg * 8) ^ ((l4 & 7) << 3);
                bx[mi] = *(const bf16x8*)&As[cur][idx];
            }
            __builtin_amdgcn_s_setprio(1);
            #pragma unroll
            for (int t = 0; t < 8; ++t)
                #pragma unroll
                for (int mi = 0; mi < 2; ++mi)
                    acc[mi][t] = __builtin_amdgcn_mfma_f32_16x16x32_bf16(aw[t], bx[mi], acc[mi][t], 0, 0, 0);
            __builtin_amdgcn_s_setprio(0);
        }
    }

    // ---- stage P (flat, conflict-free) + gamma/beta to LDS ----
    #pragma unroll
    for (int i = 0; i < 2; ++i) *(f32x4*)&P_lds[i * 1024 + tid * 4] = pv[i];
    {
        int c = tid * 4;
        if (tid < 128) *(f32x4*)&GB[0][c]       = gb;
        else           *(f32x4*)&GB[1][c - 512] = gb;
    }
    __syncthreads();

    // ---- add P (broadcast LDS reads) ----
    #pragma unroll
    for (int mi = 0; mi < 2; ++mi) {
        int lp = mi * 2 + (l4 >> 3);
        #pragma unroll
        for (int t = 0; t < 8; ++t) {
            f32x4 p4 = *(const f32x4*)&P_lds[lp * 512 + wn * 128 + t * 16 + kg * 4];
            acc[mi][t] += p4;
        }
    }

    // ---- LN stats: in-register row sums + 2-step kg reduction ----
    float S[2], Q[2];
    #pragma unroll
    for (int mi = 0; mi < 2; ++mi) {
        float s = 0.f, q = 0.f;
        #pragma unroll
        for (int t = 0; t < 8; ++t)
            #pragma unroll
            for (int j = 0; j < 4; ++j) {
                float v = acc[mi][t][j];
                s += v; q = __builtin_fmaf(v, v, q);
            }
        s += __shfl_xor(s, 16); q += __shfl_xor(q, 16);
        s += __shfl_xor(s, 32); q += __shfl_xor(q, 32);
        S[mi] = s; Q[mi] = q;
    }
    if (lane < 16) {
        #pragma unroll
        for (int mi = 0; mi < 2; ++mi) {
            red[wn][mi * 16 + l4][0] = S[mi];
            red[wn][mi * 16 + l4][1] = Q[mi];
        }
    }
    __syncthreads();

    // ---- normalize (2 fma/elem) + nonsat + vector stores ----
    #pragma unroll
    for (int mi = 0; mi < 2; ++mi) {
        int r = mi * 16 + l4;
        float Ss = red[0][r][0] + red[1][r][0] + red[2][r][0] + red[3][r][0];
        float Qs = red[0][r][1] + red[1][r][1] + red[2][r][1] + red[3][r][1];
        float mean = Ss * (1.0f / 512.0f);
        float var  = Qs * (1.0f / 512.0f) - mean * mean;
        float rstd = rsqrtf(var + 1e-5f);
        float nmrs = -mean * rstd;
        float* orow = out + (size_t)(m0 + r) * DMODEL;
        #pragma unroll
        for (int t = 0; t < 8; ++t) {
            int n = wn * 128 + t * 16 + kg * 4;
            f32x4 g4 = *(const f32x4*)&GB[0][n];
            f32x4 b4 = *(const f32x4*)&GB[1][n];
            f32x4 o;
            #pragma unroll
            for (int j = 0; j < 4; ++j) {
                float z = __builtin_fmaf(acc[mi][t][j], rstd, nmrs);
                float v = __builtin_fmaf(z, g4[j], b4[j]);
                o[j] = nonsat(v);
            }
            *(f32x4*)(orow + n) = o;
        }
    }
}

// ---------- fallback (no workspace) ----------
__global__ __launch_bounds__(256) void fallback_fwd(
    const float* __restrict__ x, const float* __restrict__ Wf,
    const float* __restrict__ bias, const float* __restrict__ gamma,
    const float* __restrict__ beta, const float* __restrict__ pe,
    float* __restrict__ out)
{
    const int tid  = threadIdx.x;
    const int wave = tid >> 6;
    const int lane = tid & 63;
    const int lrow = lane & 15;
    const int kgrp = lane >> 4;
    const int n0   = wave * 128;
    const int m0   = blockIdx.x * 32;

    f32x4 acc[2][8];
    #pragma unroll
    for (int a = 0; a < 2; ++a)
        #pragma unroll
        for (int t = 0; t < 8; ++t) acc[a][t] = (f32x4){0.f,0.f,0.f,0.f};

    const int mA[2] = { m0 + lrow, m0 + 16 + lrow };
    for (int ks = 0; ks < 32; ++ks) {
        const int kb = ks * 32 + kgrp * 8;
        bf16x8 afrag[2];
        #pragma unroll
        for (int a = 0; a < 2; ++a) {
            const float* src = (kb < 512)
                ? (x  + (size_t)mA[a] * 512 + kb)
                : (pe + (size_t)(mA[a] >> 3) * 512 + (kb - 512));
            f32x4 lo = *(const f32x4*)src;
            f32x4 hi = *(const f32x4*)(src + 4);
            bf16x8 v;
            v[0]=f2bf(lo[0]); v[1]=f2bf(lo[1]); v[2]=f2bf(lo[2]); v[3]=f2bf(lo[3]);
            v[4]=f2bf(hi[0]); v[5]=f2bf(hi[1]); v[6]=f2bf(hi[2]); v[7]=f2bf(hi[3]);
            afrag[a] = v;
        }
        #pragma unroll
        for (int t = 0; t < 8; ++t) {
            const int n = n0 + t * 16 + lrow;
            const float* wsrc = Wf + (size_t)n * KFULL + kb;
            f32x4 lo = *(const f32x4*)wsrc;
            f32x4 hi = *(const f32x4*)(wsrc + 4);
            bf16x8 bfr;
            bfr[0]=f2bf(lo[0]); bfr[1]=f2bf(lo[1]); bfr[2]=f2bf(lo[2]); bfr[3]=f2bf(lo[3]);
            bfr[4]=f2bf(hi[0]); bfr[5]=f2bf(hi[1]); bfr[6]=f2bf(hi[2]); bfr[7]=f2bf(hi[3]);
            acc[0][t] = __builtin_amdgcn_mfma_f32_16x16x32_bf16(afrag[0], bfr, acc[0][t], 0, 0, 0);
            acc[1][t] = __builtin_amdgcn_mfma_f32_16x16x32_bf16(afrag[1], bfr, acc[1][t], 0, 0, 0);
        }
    }
    __shared__ float red[4][32][2];
    float bcol[8], gcol[8], ecol[8];
    #pragma unroll
    for (int t = 0; t < 8; ++t) {
        const int n = n0 + t * 16 + lrow;
        bcol[t] = bias[n]; gcol[t] = gamma[n]; ecol[t] = beta[n];
    }
    #pragma unroll
    for (int a = 0; a < 2; ++a)
        #pragma unroll
        for (int t = 0; t < 8; ++t)
            #pragma unroll
            for (int j = 0; j < 4; ++j) acc[a][t][j] += bcol[t];
    float sm[2][4], sq[2][4];
    #pragma unroll
    for (int a = 0; a < 2; ++a)
        #pragma unroll
        for (int j = 0; j < 4; ++j) {
            float s = 0.f, q = 0.f;
            #pragma unroll
            for (int t = 0; t < 8; ++t) { float v = acc[a][t][j]; s += v; q += v * v; }
            #pragma unroll
            for (int msk = 1; msk <= 8; msk <<= 1) {
                s += __shfl_xor(s, msk, 64);
                q += __shfl_xor(q, msk, 64);
            }
            sm[a][j] = s; sq[a][j] = q;
        }
    if (lrow == 0) {
        #pragma unroll
        for (int a = 0; a < 2; ++a)
            #pragma unroll
            for (int j = 0; j < 4; ++j) {
                int r = a * 16 + kgrp * 4 + j;
                red[wave][r][0] = sm[a][j];
                red[wave][r][1] = sq[a][j];
            }
    }
    __syncthreads();
    #pragma unroll
    for (int a = 0; a < 2; ++a)
        #pragma unroll
        for (int j = 0; j < 4; ++j) {
            const int r = a * 16 + kgrp * 4 + j;
            float Ss = red[0][r][0] + red[1][r][0] + red[2][r][0] + red[3][r][0];
            float Qs = red[0][r][1] + red[1][r][1] + red[2][r][1] + red[3][r][1];
            float mean = Ss * (1.0f / 512.0f);
            float var  = Qs * (1.0f / 512.0f) - mean * mean;
            float rstd = rsqrtf(var + 1e-5f);
            const int m = m0 + a * 16 + kgrp * 4 + j;
            float* orow = out + (size_t)m * 512;
            #pragma unroll
            for (int t = 0; t < 8; ++t) {
                const int n = n0 + t * 16 + lrow;
                float v = (acc[a][t][j] - mean) * rstd * gcol[t] + ecol[t];
                orow[n] = nonsat(v);
            }
        }
}

extern "C" void kernel_launch(void* const* d_in, const int* in_sizes, int n_in,
                              void* d_out, int out_size, void* d_ws, size_t ws_size,
                              hipStream_t stream) {
    const float* x     = (const float*)d_in[0];
    const float* W     = (const float*)d_in[1];
    const float* bias  = (const float*)d_in[2];
    const float* gamma = (const float*)d_in[3];
    const float* beta  = (const float*)d_in[4];
    const float* pe    = (const float*)d_in[5];
    float* out = (float*)d_out;

    const size_t WBF_BYTES = (size_t)KFULL * DMODEL * sizeof(short);   // 1 MB
    const size_t P_BYTES   = (size_t)SEQL * DMODEL * sizeof(float);    // 8 MB

    if (ws_size >= WBF_BYTES + P_BYTES) {
        short* Wbf = (short*)d_ws;
        float* P   = (float*)((char*)d_ws + WBF_BYTES);
        cvt_w<<<dim3((DMODEL * KFULL) / (256 * 8)), dim3(256), 0, stream>>>(W, Wbf);
        pe_gemm<<<dim3(SEQL / 32), dim3(256), 0, stream>>>(pe, Wbf, bias, P);
        main_fused<<<dim3(MROWS / 32), dim3(256), 0, stream>>>(x, Wbf, P, gamma, beta, out);
    } else {
        fallback_fwd<<<dim3(MROWS / 32), dim3(256), 0, stream>>>(x, W, bias, gamma, beta, pe, out);
    }
}

// Round 10
// 60.949 us; speedup vs baseline: 1.3749x; 1.0079x over previous
//
#include <hip/hip_runtime.h>
#include <hip/hip_bf16.h>

#define SEQL 4096
#define MROWS 32768
#define DMODEL 512
#define KFULL 1024

typedef __attribute__((ext_vector_type(8))) short bf16x8;
typedef __attribute__((ext_vector_type(4))) unsigned u32x4;
typedef __attribute__((ext_vector_type(4))) float f32x4;

// Packed fp32x2 -> bf16x2 (RTNE) in ONE VALU instr. Replaces a ~5-instr
// bit-trick per pair; staging conversion was a first-order VALU cost.
__device__ __forceinline__ unsigned cvt_pk2(float a, float b) {
    unsigned r;
    asm("v_cvt_pk_bf16_f32 %0, %1, %2" : "=v"(r) : "v"(a), "v"(b));
    return r;
}

// Newton for y^3/3 + y = x. |x| <= ~6 post-LN -> 5 iters, err well under bf16 floor.
__device__ __forceinline__ float nonsat(float x) {
    float y = x;
    #pragma unroll
    for (int i = 0; i < 5; ++i) {
        float y2  = y * y;
        float num = __builtin_fmaf(y2 * y, 0.66666667f, x);
        y = num * __builtin_amdgcn_rcpf(y2 + 1.0f);
    }
    return y;
}

// W (512x1024 f32 [n][k]) -> fragment-tiled bf16:
// frag f = (k/32)*32 + (n/16); lane = ((k/8)&3)*16 + (n&15); elems k..k+7.
__global__ __launch_bounds__(256) void cvt_w(const float* __restrict__ W,
                                             short* __restrict__ Wbf) {
    int t8 = blockIdx.x * 256 + threadIdx.x;
    int n = t8 >> 7;
    int k = (t8 & 127) << 3;
    f32x4 lo = *(const f32x4*)(W + (size_t)n * KFULL + k);
    f32x4 hi = *(const f32x4*)(W + (size_t)n * KFULL + k + 4);
    u32x4 v;
    v[0] = cvt_pk2(lo[0], lo[1]); v[1] = cvt_pk2(lo[2], lo[3]);
    v[2] = cvt_pk2(hi[0], hi[1]); v[3] = cvt_pk2(hi[2], hi[3]);
    int f    = (k >> 5) * 32 + (n >> 4);
    int lane = ((k >> 3) & 3) * 16 + (n & 15);
    *(u32x4*)(Wbf + (size_t)f * 512 + lane * 8) = v;
}

// pe_gemm (swapped operands): P[l][n] = (pe @ W2^T)[l][n] + bias[n]
// 32 l-rows x 512 cols per block, 4 waves, BK=64, K=512, 2 m-frags/wave.
__global__ __launch_bounds__(256, 2) void pe_gemm(const float* __restrict__ pe,
                                                  const short* __restrict__ Wbf,
                                                  const float* __restrict__ bias,
                                                  float* __restrict__ P) {
    __shared__ short As[2][32 * 64];
    const int tid  = threadIdx.x;
    const int wn   = tid >> 6;
    const int lane = tid & 63;
    const int l4   = lane & 15;
    const int kg   = lane >> 4;
    const int l0   = blockIdx.x * 32;

    f32x4 acc[2][8];
    #pragma unroll
    for (int mi = 0; mi < 2; ++mi)
        #pragma unroll
        for (int t = 0; t < 8; ++t) acc[mi][t] = (f32x4){0.f,0.f,0.f,0.f};

    const int ar = tid >> 3;
    const int kc = (tid & 7) << 3;
    const int sw = (ar & 7) << 3;
    const int sb = ar * 64 + kc;
    const float* xp = pe + (size_t)(l0 + ar) * DMODEL + kc;

    {   // step-0 stage
        f32x4 a = *(const f32x4*)xp, b = *(const f32x4*)(xp + 4);
        u32x4 v;
        v[0] = cvt_pk2(a[0], a[1]); v[1] = cvt_pk2(a[2], a[3]);
        v[2] = cvt_pk2(b[0], b[1]); v[3] = cvt_pk2(b[2], b[3]);
        *(u32x4*)&As[0][sb ^ sw] = v;
    }
    f32x4 xa = *(const f32x4*)(xp + 64), xb = *(const f32x4*)(xp + 68);

    #pragma unroll
    for (int ks = 0; ks < 8; ++ks) {
        const int cur = ks & 1;
        __syncthreads();
        if (ks < 7) {
            u32x4 v;
            v[0] = cvt_pk2(xa[0], xa[1]); v[1] = cvt_pk2(xa[2], xa[3]);
            v[2] = cvt_pk2(xb[0], xb[1]); v[3] = cvt_pk2(xb[2], xb[3]);
            *(u32x4*)&As[cur ^ 1][sb ^ sw] = v;
        }
        if (ks < 6) {
            xa = *(const f32x4*)(xp + (ks + 2) * 64);
            xb = *(const f32x4*)(xp + (ks + 2) * 64 + 4);
        }
        #pragma unroll
        for (int ksub = 0; ksub < 2; ++ksub) {
            const short* bp = Wbf + (size_t)((16 + ks * 2 + ksub) * 32 + wn * 8) * 512 + lane * 8;
            bf16x8 aw[8];
            #pragma unroll
            for (int t = 0; t < 8; ++t) aw[t] = *(const bf16x8*)(bp + (size_t)t * 512);
            bf16x8 bx[2];
            #pragma unroll
            for (int mi = 0; mi < 2; ++mi) {
                int idx = ((mi * 16 + l4) * 64 + ksub * 32 + kg * 8) ^ ((l4 & 7) << 3);
                bx[mi] = *(const bf16x8*)&As[cur][idx];
            }
            __builtin_amdgcn_s_setprio(1);
            #pragma unroll
            for (int t = 0; t < 8; ++t)
                #pragma unroll
                for (int mi = 0; mi < 2; ++mi)
                    acc[mi][t] = __builtin_amdgcn_mfma_f32_16x16x32_bf16(aw[t], bx[mi], acc[mi][t], 0, 0, 0);
            __builtin_amdgcn_s_setprio(0);
        }
    }

    #pragma unroll
    for (int mi = 0; mi < 2; ++mi)
        #pragma unroll
        for (int t = 0; t < 8; ++t) {
            int n = wn * 128 + t * 16 + kg * 4;
            f32x4 b4 = *(const f32x4*)(bias + n);
            f32x4 v = acc[mi][t] + b4;
            *(f32x4*)(P + (size_t)(l0 + mi * 16 + l4) * DMODEL + n) = v;
        }
}

// main (swapped operands): out = nonsat(LN(x @ W1^T + P[m>>3]))
// 64 m-rows x 512 cols per block, 4 waves, BK=64, K=512, 4 m-frags/wave.
// C layout: lane holds row m = mi*16 + (lane&15), cols n = wn*128 + t*16 + kg*4 + j.
__global__ __launch_bounds__(256, 2) void main_fused(
    const float* __restrict__ x, const short* __restrict__ Wbf,
    const float* __restrict__ P, const float* __restrict__ gamma,
    const float* __restrict__ beta, float* __restrict__ out)
{
    __shared__ short As[2][64 * 64];     // 16 KB
    __shared__ float P_lds[8 * 512];     // 16 KB
    __shared__ float GB[2][512];         // 4 KB
    __shared__ float red[4][64][2];      // 2 KB

    const int tid  = threadIdx.x;
    const int wn   = tid >> 6;
    const int lane = tid & 63;
    const int l4   = lane & 15;
    const int kg   = lane >> 4;
    const int m0   = blockIdx.x * 64;
    const int l0   = m0 >> 3;

    f32x4 acc[4][8];
    #pragma unroll
    for (int mi = 0; mi < 4; ++mi)
        #pragma unroll
        for (int t = 0; t < 8; ++t) acc[mi][t] = (f32x4){0.f,0.f,0.f,0.f};

    // x staging: thread -> row ar = tid/4, 16 k-elems at (tid&3)*16
    const int ar = tid >> 2;
    const int kc = (tid & 3) << 4;
    const int sw = (ar & 7) << 3;
    const int sb = ar * 64 + kc;
    const float* xp = x + (size_t)(m0 + ar) * DMODEL + kc;

    {   // step-0 stage
        f32x4 x0[4];
        #pragma unroll
        for (int i = 0; i < 4; ++i) x0[i] = *(const f32x4*)(xp + i * 4);
        u32x4 v0, v1;
        v0[0] = cvt_pk2(x0[0][0], x0[0][1]); v0[1] = cvt_pk2(x0[0][2], x0[0][3]);
        v0[2] = cvt_pk2(x0[1][0], x0[1][1]); v0[3] = cvt_pk2(x0[1][2], x0[1][3]);
        v1[0] = cvt_pk2(x0[2][0], x0[2][1]); v1[1] = cvt_pk2(x0[2][2], x0[2][3]);
        v1[2] = cvt_pk2(x0[3][0], x0[3][1]); v1[3] = cvt_pk2(x0[3][2], x0[3][3]);
        *(u32x4*)&As[0][sb ^ sw]       = v0;
        *(u32x4*)&As[0][(sb + 8) ^ sw] = v1;
    }
    f32x4 xin[4];
    #pragma unroll
    for (int i = 0; i < 4; ++i) xin[i] = *(const f32x4*)(xp + 64 + i * 4);

    f32x4 pv[4], gb;

    #pragma unroll
    for (int ks = 0; ks < 8; ++ks) {
        const int cur = ks & 1;
        __syncthreads();
        if (ks < 7) {
            u32x4 v0, v1;
            v0[0] = cvt_pk2(xin[0][0], xin[0][1]); v0[1] = cvt_pk2(xin[0][2], xin[0][3]);
            v0[2] = cvt_pk2(xin[1][0], xin[1][1]); v0[3] = cvt_pk2(xin[1][2], xin[1][3]);
            v1[0] = cvt_pk2(xin[2][0], xin[2][1]); v1[1] = cvt_pk2(xin[2][2], xin[2][3]);
            v1[2] = cvt_pk2(xin[3][0], xin[3][1]); v1[3] = cvt_pk2(xin[3][2], xin[3][3]);
            *(u32x4*)&As[cur ^ 1][sb ^ sw]       = v0;
            *(u32x4*)&As[cur ^ 1][(sb + 8) ^ sw] = v1;
        }
        if (ks < 6) {
            #pragma unroll
            for (int i = 0; i < 4; ++i) xin[i] = *(const f32x4*)(xp + (ks + 2) * 64 + i * 4);
        }
        if (ks == 6) {
            // epilogue operands; ~2 k-steps of MFMA cover the latency
            const float* Pg = P + (size_t)l0 * DMODEL;
            #pragma unroll
            for (int i = 0; i < 4; ++i) pv[i] = *(const f32x4*)(Pg + i * 1024 + tid * 4);
            int c = tid * 4;
            const float* gsrc = (tid < 128) ? (gamma + c) : (beta + c - 512);
            gb = *(const f32x4*)gsrc;
        }
        #pragma unroll
        for (int ksub = 0; ksub < 2; ++ksub) {
            const short* bp = Wbf + (size_t)((ks * 2 + ksub) * 32 + wn * 8) * 512 + lane * 8;
            bf16x8 aw[8];
            #pragma unroll
            for (int t = 0; t < 8; ++t) aw[t] = *(const bf16x8*)(bp + (size_t)t * 512);
            bf16x8 bx[4];
            #pragma unroll
            for (int mi = 0; mi < 4; ++mi) {
                int idx = ((mi * 16 + l4) * 64 + ksub * 32 + kg * 8) ^ ((l4 & 7) << 3);
                bx[mi] = *(const bf16x8*)&As[cur][idx];
            }
            __builtin_amdgcn_s_setprio(1);
            #pragma unroll
            for (int t = 0; t < 8; ++t)
                #pragma unroll
                for (int mi = 0; mi < 4; ++mi)
                    acc[mi][t] = __builtin_amdgcn_mfma_f32_16x16x32_bf16(aw[t], bx[mi], acc[mi][t], 0, 0, 0);
            __builtin_amdgcn_s_setprio(0);
        }
    }

    // ---- stage P (flat, conflict-free) + gamma/beta to LDS ----
    #pragma unroll
    for (int i = 0; i < 4; ++i) *(f32x4*)&P_lds[i * 1024 + tid * 4] = pv[i];
    {
        int c = tid * 4;
        if (tid < 128) *(f32x4*)&GB[0][c]       = gb;
        else           *(f32x4*)&GB[1][c - 512] = gb;
    }
    __syncthreads();

    // ---- add P (broadcast LDS reads) ----
    #pragma unroll
    for (int mi = 0; mi < 4; ++mi) {
        int lp = mi * 2 + (l4 >> 3);
        #pragma unroll
        for (int t = 0; t < 8; ++t) {
            f32x4 p4 = *(const f32x4*)&P_lds[lp * 512 + wn * 128 + t * 16 + kg * 4];
            acc[mi][t] += p4;
        }
    }

    // ---- LN stats: in-register row sums + 2-step kg reduction ----
    float S[4], Q[4];
    #pragma unroll
    for (int mi = 0; mi < 4; ++mi) {
        float s = 0.f, q = 0.f;
        #pragma unroll
        for (int t = 0; t < 8; ++t)
            #pragma unroll
            for (int j = 0; j < 4; ++j) {
                float v = acc[mi][t][j];
                s += v; q = __builtin_fmaf(v, v, q);
            }
        s += __shfl_xor(s, 16); q += __shfl_xor(q, 16);
        s += __shfl_xor(s, 32); q += __shfl_xor(q, 32);
        S[mi] = s; Q[mi] = q;
    }
    if (lane < 16) {
        #pragma unroll
        for (int mi = 0; mi < 4; ++mi) {
            red[wn][mi * 16 + l4][0] = S[mi];
            red[wn][mi * 16 + l4][1] = Q[mi];
        }
    }
    __syncthreads();

    // ---- normalize (2 fma/elem) + nonsat + vector stores ----
    #pragma unroll
    for (int mi = 0; mi < 4; ++mi) {
        int r = mi * 16 + l4;
        float Ss = red[0][r][0] + red[1][r][0] + red[2][r][0] + red[3][r][0];
        float Qs = red[0][r][1] + red[1][r][1] + red[2][r][1] + red[3][r][1];
        float mean = Ss * (1.0f / 512.0f);
        float var  = Qs * (1.0f / 512.0f) - mean * mean;
        float rstd = rsqrtf(var + 1e-5f);
        float nmrs = -mean * rstd;
        float* orow = out + (size_t)(m0 + r) * DMODEL;
        #pragma unroll
        for (int t = 0; t < 8; ++t) {
            int n = wn * 128 + t * 16 + kg * 4;
            f32x4 g4 = *(const f32x4*)&GB[0][n];
            f32x4 b4 = *(const f32x4*)&GB[1][n];
            f32x4 o;
            #pragma unroll
            for (int j = 0; j < 4; ++j) {
                float z = __builtin_fmaf(acc[mi][t][j], rstd, nmrs);
                float v = __builtin_fmaf(z, g4[j], b4[j]);
                o[j] = nonsat(v);
            }
            *(f32x4*)(orow + n) = o;
        }
    }
}

// ---------- fallback (no workspace) ----------
__global__ __launch_bounds__(256) void fallback_fwd(
    const float* __restrict__ x, const float* __restrict__ Wf,
    const float* __restrict__ bias, const float* __restrict__ gamma,
    const float* __restrict__ beta, const float* __restrict__ pe,
    float* __restrict__ out)
{
    const int tid  = threadIdx.x;
    const int wave = tid >> 6;
    const int lane = tid & 63;
    const int lrow = lane & 15;
    const int kgrp = lane >> 4;
    const int n0   = wave * 128;
    const int m0   = blockIdx.x * 32;

    f32x4 acc[2][8];
    #pragma unroll
    for (int a = 0; a < 2; ++a)
        #pragma unroll
        for (int t = 0; t < 8; ++t) acc[a][t] = (f32x4){0.f,0.f,0.f,0.f};

    const int mA[2] = { m0 + lrow, m0 + 16 + lrow };
    for (int ks = 0; ks < 32; ++ks) {
        const int kb = ks * 32 + kgrp * 8;
        bf16x8 afrag[2];
        #pragma unroll
        for (int a = 0; a < 2; ++a) {
            const float* src = (kb < 512)
                ? (x  + (size_t)mA[a] * 512 + kb)
                : (pe + (size_t)(mA[a] >> 3) * 512 + (kb - 512));
            f32x4 lo = *(const f32x4*)src;
            f32x4 hi = *(const f32x4*)(src + 4);
            union { u32x4 u; bf16x8 s; } cv;
            cv.u[0] = cvt_pk2(lo[0], lo[1]); cv.u[1] = cvt_pk2(lo[2], lo[3]);
            cv.u[2] = cvt_pk2(hi[0], hi[1]); cv.u[3] = cvt_pk2(hi[2], hi[3]);
            afrag[a] = cv.s;
        }
        #pragma unroll
        for (int t = 0; t < 8; ++t) {
            const int n = n0 + t * 16 + lrow;
            const float* wsrc = Wf + (size_t)n * KFULL + kb;
            f32x4 lo = *(const f32x4*)wsrc;
            f32x4 hi = *(const f32x4*)(wsrc + 4);
            union { u32x4 u; bf16x8 s; } cv;
            cv.u[0] = cvt_pk2(lo[0], lo[1]); cv.u[1] = cvt_pk2(lo[2], lo[3]);
            cv.u[2] = cvt_pk2(hi[0], hi[1]); cv.u[3] = cvt_pk2(hi[2], hi[3]);
            acc[0][t] = __builtin_amdgcn_mfma_f32_16x16x32_bf16(afrag[0], cv.s, acc[0][t], 0, 0, 0);
            acc[1][t] = __builtin_amdgcn_mfma_f32_16x16x32_bf16(afrag[1], cv.s, acc[1][t], 0, 0, 0);
        }
    }
    __shared__ float red[4][32][2];
    float bcol[8], gcol[8], ecol[8];
    #pragma unroll
    for (int t = 0; t < 8; ++t) {
        const int n = n0 + t * 16 + lrow;
        bcol[t] = bias[n]; gcol[t] = gamma[n]; ecol[t] = beta[n];
    }
    #pragma unroll
    for (int a = 0; a < 2; ++a)
        #pragma unroll
        for (int t = 0; t < 8; ++t)
            #pragma unroll
            for (int j = 0; j < 4; ++j) acc[a][t][j] += bcol[t];
    float sm[2][4], sq[2][4];
    #pragma unroll
    for (int a = 0; a < 2; ++a)
        #pragma unroll
        for (int j = 0; j < 4; ++j) {
            float s = 0.f, q = 0.f;
            #pragma unroll
            for (int t = 0; t < 8; ++t) { float v = acc[a][t][j]; s += v; q += v * v; }
            #pragma unroll
            for (int msk = 1; msk <= 8; msk <<= 1) {
                s += __shfl_xor(s, msk, 64);
                q += __shfl_xor(q, msk, 64);
            }
            sm[a][j] = s; sq[a][j] = q;
        }
    if (lrow == 0) {
        #pragma unroll
        for (int a = 0; a < 2; ++a)
            #pragma unroll
            for (int j = 0; j < 4; ++j) {
                int r = a * 16 + kgrp * 4 + j;
                red[wave][r][0] = sm[a][j];
                red[wave][r][1] = sq[a][j];
            }
    }
    __syncthreads();
    #pragma unroll
    for (int a = 0; a < 2; ++a)
        #pragma unroll
        for (int j = 0; j < 4; ++j) {
            const int r = a * 16 + kgrp * 4 + j;
            float Ss = red[0][r][0] + red[1][r][0] + red[2][r][0] + red[3][r][0];
            float Qs = red[0][r][1] + red[1][r][1] + red[2][r][1] + red[3][r][1];
            float mean = Ss * (1.0f / 512.0f);
            float var  = Qs * (1.0f / 512.0f) - mean * mean;
            float rstd = rsqrtf(var + 1e-5f);
            const int m = m0 + a * 16 + kgrp * 4 + j;
            float* orow = out + (size_t)m * 512;
            #pragma unroll
            for (int t = 0; t < 8; ++t) {
                const int n = n0 + t * 16 + lrow;
                float v = (acc[a][t][j] - mean) * rstd * gcol[t] + ecol[t];
                orow[n] = nonsat(v);
            }
        }
}

extern "C" void kernel_launch(void* const* d_in, const int* in_sizes, int n_in,
                              void* d_out, int out_size, void* d_ws, size_t ws_size,
                              hipStream_t stream) {
    const float* x     = (const float*)d_in[0];
    const float* W     = (const float*)d_in[1];
    const float* bias  = (const float*)d_in[2];
    const float* gamma = (const float*)d_in[3];
    const float* beta  = (const float*)d_in[4];
    const float* pe    = (const float*)d_in[5];
    float* out = (float*)d_out;

    const size_t WBF_BYTES = (size_t)KFULL * DMODEL * sizeof(short);   // 1 MB
    const size_t P_BYTES   = (size_t)SEQL * DMODEL * sizeof(float);    // 8 MB

    if (ws_size >= WBF_BYTES + P_BYTES) {
        short* Wbf = (short*)d_ws;
        float* P   = (float*)((char*)d_ws + WBF_BYTES);
        cvt_w<<<dim3((DMODEL * KFULL) / (256 * 8)), dim3(256), 0, stream>>>(W, Wbf);
        pe_gemm<<<dim3(SEQL / 32), dim3(256), 0, stream>>>(pe, Wbf, bias, P);
        main_fused<<<dim3(MROWS / 64), dim3(256), 0, stream>>>(x, Wbf, P, gamma, beta, out);
    } else {
        fallback_fwd<<<dim3(MROWS / 32), dim3(256), 0, stream>>>(x, W, bias, gamma, beta, pe, out);
    }
}